// Round 4
// baseline (963.700 us; speedup 1.0000x reference)
//
#include <hip/hip_runtime.h>

#define OBS_T 20
#define HID 128
#define NGATE 512
#define MB 16          // batch rows per block
#define HSTR 136       // hbuf row stride in bf16 (272B = 17*16B)

typedef __bf16 bf16x8 __attribute__((ext_vector_type(8)));
typedef __bf16 bf16x4 __attribute__((ext_vector_type(4)));
typedef float f32x4 __attribute__((ext_vector_type(4)));
typedef float f32x2 __attribute__((ext_vector_type(2)));

__device__ __forceinline__ float fast_rcp(float x) { return __builtin_amdgcn_rcpf(x); }
#if __has_builtin(__builtin_amdgcn_exp2f)
__device__ __forceinline__ float exp2_hw(float x) { return __builtin_amdgcn_exp2f(x); }
#else
__device__ __forceinline__ float exp2_hw(float x) { return __expf(x * 0.69314718056f); }
#endif
#define LOG2E 1.442695041f

// gate scale: preacts arrive PRE-SCALED by s_q so exp2 needs no mul.
// s_q = -LOG2E for i,f,o ; -2*LOG2E for g (since tanh uses e^{-2x})
__device__ __host__ __forceinline__ float gate_scale(int q) {
  return (q == 2) ? (-2.0f * LOG2E) : (-LOG2E);
}

// ---- prep 1: fold embedding into rank-2 + bias, gate-major permutation ----
// gate row r = q*128 + j (torch i,f,g,o). np = (j>>4)*64 + q*16 + (j&15)
// Values pre-scaled by gate_scale(q).
__global__ void prep_vec(const float* __restrict__ W_emb, const float* __restrict__ b_emb,
                         const float* __restrict__ W_ih, const float* __restrict__ b_ih,
                         const float* __restrict__ b_hh,
                         float* __restrict__ biasp, float* __restrict__ wx0p,
                         float* __restrict__ wx1p) {
  int r = blockIdx.x * blockDim.x + threadIdx.x;
  if (r >= NGATE) return;
  float s0 = 0.f, s1 = 0.f, sb = 0.f;
  for (int d = 0; d < 64; ++d) {
    float w = W_ih[r * 64 + d];
    s0 += w * W_emb[d * 2 + 0];
    s1 += w * W_emb[d * 2 + 1];
    sb += w * b_emb[d];
  }
  int q = r >> 7, j = r & 127;
  float sc = gate_scale(q);
  int np = (j >> 4) * 64 + q * 16 + (j & 15);
  biasp[np] = (b_ih[r] + b_hh[r] + sb) * sc;
  wx0p[np] = s0 * sc;
  wx1p[np] = s1 * sc;
}

// ---- prep 2: W_hh -> bf16 B-fragments (r6/r8/r10 mapping), PRE-SCALED ----
__global__ void prep_wp(const float* __restrict__ W_hh, __bf16* __restrict__ Wp) {
  int tid = blockIdx.x * blockDim.x + threadIdx.x;  // 0..65535
  int jj = tid & 7;
  int lane = (tid >> 3) & 63;
  int frag = tid >> 9;  // 0..127
  int ks = frag & 3;
  int q = (frag >> 2) & 3;
  int g16 = frag >> 4;
  int cn = lane & 15, quad = lane >> 4;
  int r = q * 128 + g16 * 16 + cn;
  int k = ks * 32 + quad * 8 + jj;
  Wp[tid] = (__bf16)(W_hh[r * 128 + k] * gate_scale(q));
}

// ---- packed (f32x2) helpers: scalar transcendentals, VOP3P-packable arith ----
__device__ __forceinline__ f32x2 exp2_2(f32x2 v) {
  f32x2 r;
  r.x = exp2_hw(v.x);
  r.y = exp2_hw(v.y);
  return r;
}
__device__ __forceinline__ f32x2 rcp_2(f32x2 v) {
  f32x2 r;
  r.x = fast_rcp(v.x);
  r.y = fast_rcp(v.y);
  return r;
}
__device__ __forceinline__ f32x2 splat2(float s) {
  f32x2 v;
  v.x = s;
  v.y = s;
  return v;
}

// lane-local LSTM cell on PRE-SCALED preacts, PAIRED over two adjacent
// accumulator rows (acc[q].xy / .zw — natural even-aligned VGPR pairs from
// the MFMA C-layout). Same math as the scalar chain (absmax 1.95e-3,
// R2/R3-verified packed).
__device__ __forceinline__ f32x2 cell_update_pk(f32x2 gi, f32x2 gf, f32x2 gg,
                                                f32x2 go, f32x2& c) {
  f32x2 e_i = exp2_2(gi);
  f32x2 e_f = exp2_2(gf);
  f32x2 e_g = exp2_2(gg);
  f32x2 e_o = exp2_2(go);
  f32x2 a_i = e_i + 1.f;
  f32x2 a_f = e_f + 1.f;
  f32x2 a_g = e_g + 1.f;
  f32x2 bg = 1.f - e_g;  // == 2 - a_g
  f32x2 m1 = a_i * a_g;
  f32x2 r = rcp_2(m1 * a_f);
  f32x2 t = c * m1 + bg * a_f;  // contracts to v_pk_fma
  c = t * r;
  f32x2 e_c = exp2_2(c * (-2.f * LOG2E));
  f32x2 a_c = e_c + 1.f;
  f32x2 bc = 1.f - e_c;  // == 2 - a_c
  return bc * rcp_2((e_o + 1.f) * a_c);
}

// One LSTM timestep. CUR/NXT are LITERAL buffer indices (R4: manual 2x unroll
// makes all hbuf addresses compile-time-constant — removes per-iter address
// recompute; R3 proved we're issue-throughput-bound, so every instr counts).
#define STEP_BODY(CUR, NXT, T)                                                 \
  {                                                                            \
    const int t_ = (T);                                                        \
    f32x2 x01 = *(const f32x2*)&obs_sx[t_][quad * 4];                          \
    f32x2 x23 = *(const f32x2*)&obs_sx[t_][quad * 4 + 2];                      \
    f32x2 y01 = *(const f32x2*)&obs_sy[t_][quad * 4];                          \
    f32x2 y23 = *(const f32x2*)&obs_sy[t_][quad * 4 + 2];                      \
    f32x4 acc[4];                                                              \
    _Pragma("unroll") for (int q = 0; q < 4; ++q) {                            \
      f32x2 b2 = splat2(bias_v[q]);                                            \
      f32x2 w0 = splat2(w0r[q]);                                               \
      f32x2 w1 = splat2(w1r[q]);                                               \
      f32x2 lo = x01 * w0 + (y01 * w1 + b2);                                   \
      f32x2 hi = x23 * w0 + (y23 * w1 + b2);                                   \
      acc[q].x = lo.x;                                                         \
      acc[q].y = lo.y;                                                         \
      acc[q].z = hi.x;                                                         \
      acc[q].w = hi.y;                                                         \
    }                                                                          \
    _Pragma("unroll") for (int ks = 0; ks < 4; ++ks) {                         \
      bf16x8 Av = *(const bf16x8*)&hbuf[CUR][cn][ks * 32 + quad * 8];          \
      _Pragma("unroll") for (int q = 0; q < 4; ++q)                            \
        acc[q] = __builtin_amdgcn_mfma_f32_16x16x32_bf16(Av, Bf[ks][q],        \
                                                         acc[q], 0, 0, 0);     \
    }                                                                          \
    f32x2 hlo =                                                                \
        cell_update_pk(acc[0].xy, acc[1].xy, acc[2].xy, acc[3].xy, cc2[0]);    \
    f32x2 hhi =                                                                \
        cell_update_pk(acc[0].zw, acc[1].zw, acc[2].zw, acc[3].zw, cc2[1]);    \
    hbuf[NXT][quad * 4 + 0][ju] = (__bf16)hlo.x;                               \
    hbuf[NXT][quad * 4 + 1][ju] = (__bf16)hlo.y;                               \
    hbuf[NXT][quad * 4 + 2][ju] = (__bf16)hhi.x;                               \
    hbuf[NXT][quad * 4 + 3][ju] = (__bf16)hhi.y;                               \
    __syncthreads();                                                           \
  }

// ---- main fused LSTM (R4 instruction diet on the R3 8-wave structure):
// 512 threads = 8 waves, wave wv owns ONE unit-group; 2 blocks/CU = 4
// waves/SIMD (R3-proven occupancy). R3 showed per-SIMD throughput saturated
// (VALU 61% + MFMA 28% ~= full issue) — so R4 removes instructions:
//   (1) wx+bias in regs (12 regs; safe now — R1's failure was the 252-reg
//       structure, we're at 64 with a 128 cap),
//   (2) SoA obs + v_pk_fma acc-init (32 scalar FMA -> 16 pk),
//   (3) literal-index 2x-unrolled time loop (no per-iter hbuf addressing).
// Tripwire: WRITE_SIZE must stay 32768 KB; if it balloons, the 128-reg cap
// spilled — revert (1).
__global__ __launch_bounds__(512, 4) void lstm_fused(
    const float* __restrict__ obs, const float* __restrict__ h0,
    const float* __restrict__ c0, const __bf16* __restrict__ Wp,
    const float* __restrict__ biasp, const float* __restrict__ wx0p,
    const float* __restrict__ wx1p, float* __restrict__ out, int batch) {
  __shared__ __align__(16) __bf16 hbuf[2][MB][HSTR];
  __shared__ __align__(16) float obs_sx[OBS_T][MB];
  __shared__ __align__(16) float obs_sy[OBS_T][MB];

  const int tid = threadIdx.x;
  const int lane = tid & 63;
  const int wv = tid >> 6;  // 0..7 — unit-group index
  const int cn = lane & 15;
  const int quad = lane >> 4;
  const int bbase = blockIdx.x * MB;
  const int ju = wv * 16 + cn;  // this wave's output column

  // stage obs tile SoA: 20 x 16 (x,y) pairs = 320 float2 loads
  if (tid < OBS_T * MB) {
    const int t = tid >> 4, row = tid & 15;
    float2 v = ((const float2*)obs)[t * batch + bbase + row];
    obs_sx[t][row] = v.x;
    obs_sy[t][row] = v.y;
  }
  // stage h0 tile fp32 -> bf16 LDS: 16 rows x 32 float4 = 512, one per thread
  {
    int row = tid >> 5, c4 = tid & 31;
    float4 v = ((const float4*)h0)[(bbase + row) * 32 + c4];
    bf16x4 b;
    b.x = (__bf16)v.x; b.y = (__bf16)v.y; b.z = (__bf16)v.z; b.w = (__bf16)v.w;
    *(bf16x4*)&hbuf[0][row][c4 * 4] = b;
  }

  // persistent B fragments: 1 unit-group x 4 gates x 4 ksteps = 64 regs
  bf16x8 Bf[4][4];  // [ks][q]
  {
    const bf16x8* wp8 = (const bf16x8*)Wp;
#pragma unroll
    for (int q = 0; q < 4; ++q)
#pragma unroll
      for (int ks = 0; ks < 4; ++ks)
        Bf[ks][q] = wp8[(wv * 16 + q * 4 + ks) * 64 + lane];
  }

  // bias + rank-2 wx: 12 regs, loop-invariant, one-time L2-cached loads
  float bias_v[4], w0r[4], w1r[4];
#pragma unroll
  for (int q = 0; q < 4; ++q) {
    int n = wv * 64 + q * 16 + cn;
    bias_v[q] = biasp[n];
    w0r[q] = wx0p[n];
    w1r[q] = wx1p[n];
  }

  // c state as f32x2 pairs: cc2[p] = c for rows (quad*4+2p, quad*4+2p+1)
  f32x2 cc2[2];
#pragma unroll
  for (int p = 0; p < 2; ++p) {
    cc2[p].x = c0[(bbase + quad * 4 + 2 * p + 0) * HID + ju];
    cc2[p].y = c0[(bbase + quad * 4 + 2 * p + 1) * HID + ju];
  }

  __syncthreads();

  // 19 in-loop steps: t=0 (buf0->buf1), then 9 x {buf1->buf0, buf0->buf1}
  STEP_BODY(0, 1, 0)
#pragma unroll 1
  for (int tp = 0; tp < 9; ++tp) {
    STEP_BODY(1, 0, 1 + 2 * tp)
    STEP_BODY(0, 1, 2 + 2 * tp)
  }

  // peeled final step (t=19, reads buf1): h straight to global
  {
    const int t_ = OBS_T - 1;
    f32x2 x01 = *(const f32x2*)&obs_sx[t_][quad * 4];
    f32x2 x23 = *(const f32x2*)&obs_sx[t_][quad * 4 + 2];
    f32x2 y01 = *(const f32x2*)&obs_sy[t_][quad * 4];
    f32x2 y23 = *(const f32x2*)&obs_sy[t_][quad * 4 + 2];
    f32x4 acc[4];
#pragma unroll
    for (int q = 0; q < 4; ++q) {
      f32x2 b2 = splat2(bias_v[q]);
      f32x2 w0 = splat2(w0r[q]);
      f32x2 w1 = splat2(w1r[q]);
      f32x2 lo = x01 * w0 + (y01 * w1 + b2);
      f32x2 hi = x23 * w0 + (y23 * w1 + b2);
      acc[q].x = lo.x;
      acc[q].y = lo.y;
      acc[q].z = hi.x;
      acc[q].w = hi.y;
    }
#pragma unroll
    for (int ks = 0; ks < 4; ++ks) {
      bf16x8 Av = *(const bf16x8*)&hbuf[1][cn][ks * 32 + quad * 8];
#pragma unroll
      for (int q = 0; q < 4; ++q)
        acc[q] = __builtin_amdgcn_mfma_f32_16x16x32_bf16(Av, Bf[ks][q], acc[q], 0, 0, 0);
    }
    {
      f32x2 hlo = cell_update_pk(acc[0].xy, acc[1].xy, acc[2].xy, acc[3].xy, cc2[0]);
      f32x2 hhi = cell_update_pk(acc[0].zw, acc[1].zw, acc[2].zw, acc[3].zw, cc2[1]);
      out[(bbase + quad * 4 + 0) * HID + ju] = hlo.x;
      out[(bbase + quad * 4 + 1) * HID + ju] = hlo.y;
      out[(bbase + quad * 4 + 2) * HID + ju] = hhi.x;
      out[(bbase + quad * 4 + 3) * HID + ju] = hhi.y;
    }
  }
}

extern "C" void kernel_launch(void* const* d_in, const int* in_sizes, int n_in,
                              void* d_out, int out_size, void* d_ws, size_t ws_size,
                              hipStream_t stream) {
  const float* obs = (const float*)d_in[0];
  const float* h0 = (const float*)d_in[1];
  const float* c0 = (const float*)d_in[2];
  const float* W_emb = (const float*)d_in[3];
  const float* b_emb = (const float*)d_in[4];
  const float* W_ih = (const float*)d_in[5];
  const float* W_hh = (const float*)d_in[6];
  const float* b_ih = (const float*)d_in[7];
  const float* b_hh = (const float*)d_in[8];
  float* out = (float*)d_out;
  const int batch = in_sizes[1] / HID;

  __bf16* Wp = (__bf16*)d_ws;                     // 65536 bf16 = 128 KB
  float* biasp = (float*)((char*)d_ws + 131072);  // 3 x 512 f32
  float* wx0p = biasp + NGATE;
  float* wx1p = wx0p + NGATE;

  prep_vec<<<2, 256, 0, stream>>>(W_emb, b_emb, W_ih, b_ih, b_hh, biasp, wx0p, wx1p);
  prep_wp<<<256, 256, 0, stream>>>(W_hh, Wp);
  lstm_fused<<<batch / MB, 512, 0, stream>>>(obs, h0, c0, Wp, biasp, wx0p, wx1p, out, batch);
}

// Round 5
// 366.495 us; speedup vs baseline: 2.6295x; 2.6295x over previous
//
#include <hip/hip_runtime.h>

#define OBS_T 20
#define HID 128
#define NGATE 512
#define MB 16          // batch rows per TILE
#define NTILE 2        // independent batch tiles per block (in-wave pipeline)
#define HSTR 136       // hbuf row stride in bf16 (272B = 17*16B)

typedef __bf16 bf16x8 __attribute__((ext_vector_type(8)));
typedef __bf16 bf16x4 __attribute__((ext_vector_type(4)));
typedef float f32x4 __attribute__((ext_vector_type(4)));
typedef float f32x2 __attribute__((ext_vector_type(2)));

__device__ __forceinline__ float fast_rcp(float x) { return __builtin_amdgcn_rcpf(x); }
#if __has_builtin(__builtin_amdgcn_exp2f)
__device__ __forceinline__ float exp2_hw(float x) { return __builtin_amdgcn_exp2f(x); }
#else
__device__ __forceinline__ float exp2_hw(float x) { return __expf(x * 0.69314718056f); }
#endif
#define LOG2E 1.442695041f

// gate scale: preacts arrive PRE-SCALED by s_q so exp2 needs no mul.
// s_q = -LOG2E for i,f,o ; -2*LOG2E for g (since tanh uses e^{-2x})
__device__ __host__ __forceinline__ float gate_scale(int q) {
  return (q == 2) ? (-2.0f * LOG2E) : (-LOG2E);
}

// ---- prep 1: fold embedding into rank-2 + bias, gate-major permutation ----
// gate row r = q*128 + j (torch i,f,g,o). np = (j>>4)*64 + q*16 + (j&15)
// Values pre-scaled by gate_scale(q).
__global__ void prep_vec(const float* __restrict__ W_emb, const float* __restrict__ b_emb,
                         const float* __restrict__ W_ih, const float* __restrict__ b_ih,
                         const float* __restrict__ b_hh,
                         float* __restrict__ biasp, float* __restrict__ wx0p,
                         float* __restrict__ wx1p) {
  int r = blockIdx.x * blockDim.x + threadIdx.x;
  if (r >= NGATE) return;
  float s0 = 0.f, s1 = 0.f, sb = 0.f;
  for (int d = 0; d < 64; ++d) {
    float w = W_ih[r * 64 + d];
    s0 += w * W_emb[d * 2 + 0];
    s1 += w * W_emb[d * 2 + 1];
    sb += w * b_emb[d];
  }
  int q = r >> 7, j = r & 127;
  float sc = gate_scale(q);
  int np = (j >> 4) * 64 + q * 16 + (j & 15);
  biasp[np] = (b_ih[r] + b_hh[r] + sb) * sc;
  wx0p[np] = s0 * sc;
  wx1p[np] = s1 * sc;
}

// ---- prep 2: W_hh -> bf16 B-fragments (r6/r8/r10 mapping), PRE-SCALED ----
__global__ void prep_wp(const float* __restrict__ W_hh, __bf16* __restrict__ Wp) {
  int tid = blockIdx.x * blockDim.x + threadIdx.x;  // 0..65535
  int jj = tid & 7;
  int lane = (tid >> 3) & 63;
  int frag = tid >> 9;  // 0..127
  int ks = frag & 3;
  int q = (frag >> 2) & 3;
  int g16 = frag >> 4;
  int cn = lane & 15, quad = lane >> 4;
  int r = q * 128 + g16 * 16 + cn;
  int k = ks * 32 + quad * 8 + jj;
  Wp[tid] = (__bf16)(W_hh[r * 128 + k] * gate_scale(q));
}

// ---- packed (f32x2) helpers: scalar transcendentals, VOP3P-packable arith ----
__device__ __forceinline__ f32x2 exp2_2(f32x2 v) {
  f32x2 r;
  r.x = exp2_hw(v.x);
  r.y = exp2_hw(v.y);
  return r;
}
__device__ __forceinline__ f32x2 rcp_2(f32x2 v) {
  f32x2 r;
  r.x = fast_rcp(v.x);
  r.y = fast_rcp(v.y);
  return r;
}

// lane-local LSTM cell on PRE-SCALED preacts, PAIRED over two adjacent
// accumulator rows (acc[q].xy / .zw — natural even-aligned VGPR pairs from
// the MFMA C-layout). Same math as the scalar chain (absmax 1.95e-3,
// R2/R3-verified packed).
__device__ __forceinline__ f32x2 cell_update_pk(f32x2 gi, f32x2 gf, f32x2 gg,
                                                f32x2 go, f32x2& c) {
  f32x2 e_i = exp2_2(gi);
  f32x2 e_f = exp2_2(gf);
  f32x2 e_g = exp2_2(gg);
  f32x2 e_o = exp2_2(go);
  f32x2 a_i = e_i + 1.f;
  f32x2 a_f = e_f + 1.f;
  f32x2 a_g = e_g + 1.f;
  f32x2 bg = 1.f - e_g;  // == 2 - a_g
  f32x2 m1 = a_i * a_g;
  f32x2 r = rcp_2(m1 * a_f);
  f32x2 t = c * m1 + bg * a_f;  // contracts to v_pk_fma
  c = t * r;
  f32x2 e_c = exp2_2(c * (-2.f * LOG2E));
  f32x2 a_c = e_c + 1.f;
  f32x2 bc = 1.f - e_c;  // == 2 - a_c
  return bc * rcp_2((e_o + 1.f) * a_c);
}

// ---- main fused LSTM, R5: two-tile in-wave pipeline at 2 waves/SIMD ----
// LEDGER LESSON (R1/R4 spills): Bf lives in AGPRs, invisible to VGPR_Count.
// R3's "VGPR 64" was 64 arch + 64 AGPR = 128 unified = EXACTLY the 4-wave
// cap — zero headroom; R4's +12-reg wx hoist forced the 2.3 GB scratch
// disaster. R3 also proved occupancy (2 vs 4 waves/SIMD) is perf-neutral:
// we're per-SIMD throughput-bound, dominated by the transcendental phase
// (~45% of wall) which barriers phase-lock across waves.
// R5 therefore runs 2 waves/SIMD (256-reg budget, launch_bounds(512,2) ->
// 1 block/CU) and spends the register headroom on TWO independent batch
// tiles per block sharing Bf/wx/bias: tile1's MFMA+acc-init issues under
// tile0's trans chain (no dependence), and barriers amortize 2x.
// Unified ledger: Bf 64(AGPR) + acc 32 + cc 8 + wx/bias 12 + temps ~35
// ~= 150 << 256. Tripwire: WRITE_SIZE must be exactly 32768 KB and FETCH
// ~38.5 MB — any ballooning = spill, revert.
__global__ __launch_bounds__(512, 2) void lstm_fused(
    const float* __restrict__ obs, const float* __restrict__ h0,
    const float* __restrict__ c0, const __bf16* __restrict__ Wp,
    const float* __restrict__ biasp, const float* __restrict__ wx0p,
    const float* __restrict__ wx1p, float* __restrict__ out, int batch) {
  __shared__ __align__(16) __bf16 hbuf[NTILE][2][MB][HSTR];
  __shared__ __align__(16) float obs_s[NTILE][OBS_T][MB][2];

  const int tid = threadIdx.x;
  const int lane = tid & 63;
  const int wv = tid >> 6;  // 0..7 — unit-group index
  const int cn = lane & 15;
  const int quad = lane >> 4;
  const int bbase = blockIdx.x * (MB * NTILE);
  const int ju = wv * 16 + cn;  // this wave's output column

  // stage obs tiles: 2 x 160 float4 (R3-proven mapping per tile)
  if (tid < 2 * 160) {
    const int tl = (tid >= 160) ? 1 : 0;
    const int w = tid - tl * 160;
    const int t = w >> 3, f4 = w & 7;
    ((float4*)&obs_s[tl][0][0][0])[w] =
        ((const float4*)obs)[(t * batch + bbase + tl * MB) / 2 + f4];
  }
  // stage h0 tiles fp32 -> bf16 LDS: per tile 16 rows x 32 float4 = 512
  {
    const int row = tid >> 5, c4 = tid & 31;
#pragma unroll
    for (int tl = 0; tl < NTILE; ++tl) {
      float4 v = ((const float4*)h0)[(bbase + tl * MB + row) * 32 + c4];
      bf16x4 b;
      b.x = (__bf16)v.x; b.y = (__bf16)v.y; b.z = (__bf16)v.z; b.w = (__bf16)v.w;
      *(bf16x4*)&hbuf[tl][0][row][c4 * 4] = b;
    }
  }

  // persistent B fragments (shared by both tiles): 4 gates x 4 ksteps = 64
  // regs (AGPR side)
  bf16x8 Bf[4][4];  // [ks][q]
  {
    const bf16x8* wp8 = (const bf16x8*)Wp;
#pragma unroll
    for (int q = 0; q < 4; ++q)
#pragma unroll
      for (int ks = 0; ks < 4; ++ks)
        Bf[ks][q] = wp8[(wv * 16 + q * 4 + ks) * 64 + lane];
  }

  // bias + rank-2 wx in regs (12): loop-invariant, shared by both tiles.
  // Affordable NOW because the 2-wave budget is 256 (R1/R4 failed this at
  // their respective caps).
  float bias_v[4], w0r[4], w1r[4];
#pragma unroll
  for (int q = 0; q < 4; ++q) {
    int n = wv * 64 + q * 16 + cn;
    bias_v[q] = biasp[n];
    w0r[q] = wx0p[n];
    w1r[q] = wx1p[n];
  }

  // c state as f32x2 pairs per tile: cc2[tl][p] = rows (quad*4+2p, +1)
  f32x2 cc2[NTILE][2];
#pragma unroll
  for (int tl = 0; tl < NTILE; ++tl)
#pragma unroll
    for (int p = 0; p < 2; ++p) {
      cc2[tl][p].x = c0[(bbase + tl * MB + quad * 4 + 2 * p + 0) * HID + ju];
      cc2[tl][p].y = c0[(bbase + tl * MB + quad * 4 + 2 * p + 1) * HID + ju];
    }

  __syncthreads();

  int cur = 0;
#pragma unroll 1
  for (int t = 0; t < OBS_T - 1; ++t) {
    // Phase 1 (both tiles): acc init + MFMA. Tile1's MFMAs are independent
    // of tile0's cell chain -> scheduler overlaps them with Phase 2.
    f32x4 acc[NTILE][4];  // [tl][q]
#pragma unroll
    for (int tl = 0; tl < NTILE; ++tl) {
#pragma unroll
      for (int q = 0; q < 4; ++q) {
        float w0q = w0r[q], w1q = w1r[q];
#pragma unroll
        for (int r = 0; r < 4; ++r) {
          float2 ob = *(const float2*)&obs_s[tl][t][quad * 4 + r][0];
          acc[tl][q][r] = fmaf(ob.y, w1q, fmaf(ob.x, w0q, bias_v[q]));
        }
      }
#pragma unroll
      for (int ks = 0; ks < 4; ++ks) {
        bf16x8 Av = *(const bf16x8*)&hbuf[tl][cur][cn][ks * 32 + quad * 8];
#pragma unroll
        for (int q = 0; q < 4; ++q)
          acc[tl][q] = __builtin_amdgcn_mfma_f32_16x16x32_bf16(Av, Bf[ks][q],
                                                               acc[tl][q], 0, 0, 0);
      }
    }

    // Phase 2 (both tiles): packed cell updates + h writes
    const int nxt = cur ^ 1;
#pragma unroll
    for (int tl = 0; tl < NTILE; ++tl) {
      f32x2 hlo = cell_update_pk(acc[tl][0].xy, acc[tl][1].xy, acc[tl][2].xy,
                                 acc[tl][3].xy, cc2[tl][0]);
      f32x2 hhi = cell_update_pk(acc[tl][0].zw, acc[tl][1].zw, acc[tl][2].zw,
                                 acc[tl][3].zw, cc2[tl][1]);
      hbuf[tl][nxt][quad * 4 + 0][ju] = (__bf16)hlo.x;
      hbuf[tl][nxt][quad * 4 + 1][ju] = (__bf16)hlo.y;
      hbuf[tl][nxt][quad * 4 + 2][ju] = (__bf16)hhi.x;
      hbuf[tl][nxt][quad * 4 + 3][ju] = (__bf16)hhi.y;
    }
    __syncthreads();
    cur = nxt;
  }

  // peeled final step (both tiles): h straight to global
  {
    const int t = OBS_T - 1;
    f32x4 acc[NTILE][4];
#pragma unroll
    for (int tl = 0; tl < NTILE; ++tl) {
#pragma unroll
      for (int q = 0; q < 4; ++q) {
        float w0q = w0r[q], w1q = w1r[q];
#pragma unroll
        for (int r = 0; r < 4; ++r) {
          float2 ob = *(const float2*)&obs_s[tl][t][quad * 4 + r][0];
          acc[tl][q][r] = fmaf(ob.y, w1q, fmaf(ob.x, w0q, bias_v[q]));
        }
      }
#pragma unroll
      for (int ks = 0; ks < 4; ++ks) {
        bf16x8 Av = *(const bf16x8*)&hbuf[tl][cur][cn][ks * 32 + quad * 8];
#pragma unroll
        for (int q = 0; q < 4; ++q)
          acc[tl][q] = __builtin_amdgcn_mfma_f32_16x16x32_bf16(Av, Bf[ks][q],
                                                               acc[tl][q], 0, 0, 0);
      }
    }
#pragma unroll
    for (int tl = 0; tl < NTILE; ++tl) {
      f32x2 hlo = cell_update_pk(acc[tl][0].xy, acc[tl][1].xy, acc[tl][2].xy,
                                 acc[tl][3].xy, cc2[tl][0]);
      f32x2 hhi = cell_update_pk(acc[tl][0].zw, acc[tl][1].zw, acc[tl][2].zw,
                                 acc[tl][3].zw, cc2[tl][1]);
      const int rb = bbase + tl * MB + quad * 4;
      out[(rb + 0) * HID + ju] = hlo.x;
      out[(rb + 1) * HID + ju] = hlo.y;
      out[(rb + 2) * HID + ju] = hhi.x;
      out[(rb + 3) * HID + ju] = hhi.y;
    }
  }
}

extern "C" void kernel_launch(void* const* d_in, const int* in_sizes, int n_in,
                              void* d_out, int out_size, void* d_ws, size_t ws_size,
                              hipStream_t stream) {
  const float* obs = (const float*)d_in[0];
  const float* h0 = (const float*)d_in[1];
  const float* c0 = (const float*)d_in[2];
  const float* W_emb = (const float*)d_in[3];
  const float* b_emb = (const float*)d_in[4];
  const float* W_ih = (const float*)d_in[5];
  const float* W_hh = (const float*)d_in[6];
  const float* b_ih = (const float*)d_in[7];
  const float* b_hh = (const float*)d_in[8];
  float* out = (float*)d_out;
  const int batch = in_sizes[1] / HID;

  __bf16* Wp = (__bf16*)d_ws;                     // 65536 bf16 = 128 KB
  float* biasp = (float*)((char*)d_ws + 131072);  // 3 x 512 f32
  float* wx0p = biasp + NGATE;
  float* wx1p = wx0p + NGATE;

  prep_vec<<<2, 256, 0, stream>>>(W_emb, b_emb, W_ih, b_ih, b_hh, biasp, wx0p, wx1p);
  prep_wp<<<256, 256, 0, stream>>>(W_hh, Wp);
  lstm_fused<<<batch / (MB * NTILE), 512, 0, stream>>>(obs, h0, c0, Wp, biasp,
                                                       wx0p, wx1p, out, batch);
}

// Round 6
// 338.629 us; speedup vs baseline: 2.8459x; 1.0823x over previous
//
#include <hip/hip_runtime.h>

#define OBS_T 20
#define HID 128
#define NGATE 512
#define MB 16          // batch rows per block
#define HSTR 136       // hbuf row stride in bf16 (272B = 17*16B)

typedef __bf16 bf16x8 __attribute__((ext_vector_type(8)));
typedef __bf16 bf16x4 __attribute__((ext_vector_type(4)));
typedef float f32x4 __attribute__((ext_vector_type(4)));
typedef float f32x2 __attribute__((ext_vector_type(2)));

__device__ __forceinline__ float fast_rcp(float x) { return __builtin_amdgcn_rcpf(x); }
#if __has_builtin(__builtin_amdgcn_exp2f)
__device__ __forceinline__ float exp2_hw(float x) { return __builtin_amdgcn_exp2f(x); }
#else
__device__ __forceinline__ float exp2_hw(float x) { return __expf(x * 0.69314718056f); }
#endif
#define LOG2E 1.442695041f

// gate scale: preacts arrive PRE-SCALED by s_q so exp2 needs no mul.
// s_q = -LOG2E for i,f,o ; -2*LOG2E for g (since tanh uses e^{-2x})
__device__ __host__ __forceinline__ float gate_scale(int q) {
  return (q == 2) ? (-2.0f * LOG2E) : (-LOG2E);
}

// ---- prep 1: fold embedding into rank-2 + bias, gate-major permutation ----
// gate row r = q*128 + j (torch i,f,g,o). np = (j>>4)*64 + q*16 + (j&15)
// R6: tables written as DUPLICATED f32x2 pairs {v,v} so the main kernel's
// packed acc-init reads them as 64-bit operands with NO splat movs.
// Layout: wxb[0][np]=w0 pair, wxb[1][np]=w1 pair, wxb[2][np]=bias pair.
__global__ void prep_vec(const float* __restrict__ W_emb, const float* __restrict__ b_emb,
                         const float* __restrict__ W_ih, const float* __restrict__ b_ih,
                         const float* __restrict__ b_hh, float2* __restrict__ wxb) {
  int r = blockIdx.x * blockDim.x + threadIdx.x;
  if (r >= NGATE) return;
  float s0 = 0.f, s1 = 0.f, sb = 0.f;
  for (int d = 0; d < 64; ++d) {
    float w = W_ih[r * 64 + d];
    s0 += w * W_emb[d * 2 + 0];
    s1 += w * W_emb[d * 2 + 1];
    sb += w * b_emb[d];
  }
  int q = r >> 7, j = r & 127;
  float sc = gate_scale(q);
  int np = (j >> 4) * 64 + q * 16 + (j & 15);
  float w0 = s0 * sc, w1 = s1 * sc, bb = (b_ih[r] + b_hh[r] + sb) * sc;
  wxb[0 * NGATE + np] = make_float2(w0, w0);
  wxb[1 * NGATE + np] = make_float2(w1, w1);
  wxb[2 * NGATE + np] = make_float2(bb, bb);
}

// ---- prep 2: W_hh -> bf16 B-fragments (r6/r8/r10 mapping), PRE-SCALED ----
__global__ void prep_wp(const float* __restrict__ W_hh, __bf16* __restrict__ Wp) {
  int tid = blockIdx.x * blockDim.x + threadIdx.x;  // 0..65535
  int jj = tid & 7;
  int lane = (tid >> 3) & 63;
  int frag = tid >> 9;  // 0..127
  int ks = frag & 3;
  int q = (frag >> 2) & 3;
  int g16 = frag >> 4;
  int cn = lane & 15, quad = lane >> 4;
  int r = q * 128 + g16 * 16 + cn;
  int k = ks * 32 + quad * 8 + jj;
  Wp[tid] = (__bf16)(W_hh[r * 128 + k] * gate_scale(q));
}

// ---- packed (f32x2) helpers: scalar transcendentals, VOP3P-packable arith ----
__device__ __forceinline__ f32x2 exp2_2(f32x2 v) {
  f32x2 r;
  r.x = exp2_hw(v.x);
  r.y = exp2_hw(v.y);
  return r;
}
__device__ __forceinline__ f32x2 rcp_2(f32x2 v) {
  f32x2 r;
  r.x = fast_rcp(v.x);
  r.y = fast_rcp(v.y);
  return r;
}

// lane-local LSTM cell on PRE-SCALED preacts, PAIRED over two adjacent
// accumulator rows (acc[q].xy / .zw — natural even-aligned VGPR pairs from
// the MFMA C-layout). Same math as the scalar chain (absmax 1.95e-3,
// R2/R3-verified packed).
__device__ __forceinline__ f32x2 cell_update_pk(f32x2 gi, f32x2 gf, f32x2 gg,
                                                f32x2 go, f32x2& c) {
  f32x2 e_i = exp2_2(gi);
  f32x2 e_f = exp2_2(gf);
  f32x2 e_g = exp2_2(gg);
  f32x2 e_o = exp2_2(go);
  f32x2 a_i = e_i + 1.f;
  f32x2 a_f = e_f + 1.f;
  f32x2 a_g = e_g + 1.f;
  f32x2 bg = 1.f - e_g;  // == 2 - a_g
  f32x2 m1 = a_i * a_g;
  f32x2 r = rcp_2(m1 * a_f);
  f32x2 t = c * m1 + bg * a_f;  // contracts to v_pk_fma
  c = t * r;
  f32x2 e_c = exp2_2(c * (-2.f * LOG2E));
  f32x2 a_c = e_c + 1.f;
  f32x2 bc = 1.f - e_c;  // == 2 - a_c
  return bc * rcp_2((e_o + 1.f) * a_c);
}

// Packed acc-init from duplicated-pair LDS tables. 12 ds_read_b64 (single
// shared base + offset immediates) + 16 v_pk_fma — replaces R3's 32 scalar
// FMAs. FMA nesting order matches R3 exactly: y*w1 + (x*w0 + b).
#define ACC_INIT(T)                                                            \
  do {                                                                         \
    f32x2 x01 = *(const f32x2*)&obs_sx[(T)][quad * 4];                         \
    f32x2 x23 = *(const f32x2*)&obs_sx[(T)][quad * 4 + 2];                     \
    f32x2 y01 = *(const f32x2*)&obs_sy[(T)][quad * 4];                         \
    f32x2 y23 = *(const f32x2*)&obs_sy[(T)][quad * 4 + 2];                     \
    _Pragma("unroll") for (int q = 0; q < 4; ++q) {                            \
      const int n = wv * 64 + q * 16 + cn;                                     \
      f32x2 w0 = *(const f32x2*)&wxb_s[0][n][0];                               \
      f32x2 w1 = *(const f32x2*)&wxb_s[1][n][0];                               \
      f32x2 b2 = *(const f32x2*)&wxb_s[2][n][0];                               \
      f32x2 lo = y01 * w1 + (x01 * w0 + b2);                                   \
      f32x2 hi = y23 * w1 + (x23 * w0 + b2);                                   \
      acc[q].x = lo.x;                                                         \
      acc[q].y = lo.y;                                                         \
      acc[q].z = hi.x;                                                         \
      acc[q].w = hi.y;                                                         \
    }                                                                          \
  } while (0)

// ---- main fused LSTM, R6: R3 structure + instruction diet + barrier-shadow
// pipelining. 512 threads = 8 waves, wave wv owns ONE unit-group; 2 blocks/CU
// = 4 waves/SIMD (R3/R5 PROVEN: 2 co-resident blocks with independent
// barriers is load-bearing — R5's 1-block/CU variant lost 13%).
// Ledger (R1/R4 lesson — Bf is AGPR, invisible to VGPR_Count): Bf 64 AGPR +
// arch ≤64 must hold at the 4-wave 128-unified cap. R6 is reg-neutral vs R3:
// bias moves OUT of regs into the duplicated LDS table (−4), acc extends its
// live range across the barrier but below the cell-phase peak.
// Changes vs R3:
//  (1) packed acc-init from duplicated-f32x2 LDS tables (no splat movs),
//  (2) ACC_INIT(t+1) placed between h-write and __syncthreads — fills the
//      barrier-convergence idle with the next step's h-independent work
//      (syncthreads is a scheduling fence, so the placement sticks).
// Tripwire: WRITE_SIZE must stay exactly 32768 KB, FETCH ~38.5 MB.
__global__ __launch_bounds__(512, 4) void lstm_fused(
    const float* __restrict__ obs, const float* __restrict__ h0,
    const float* __restrict__ c0, const __bf16* __restrict__ Wp,
    const float* __restrict__ wxbp, float* __restrict__ out, int batch) {
  __shared__ __align__(16) __bf16 hbuf[2][MB][HSTR];
  __shared__ __align__(16) float obs_sx[OBS_T][MB];
  __shared__ __align__(16) float obs_sy[OBS_T][MB];
  __shared__ __align__(16) float wxb_s[3][NGATE][2];  // duplicated pairs

  const int tid = threadIdx.x;
  const int lane = tid & 63;
  const int wv = tid >> 6;  // 0..7 — unit-group index
  const int cn = lane & 15;
  const int quad = lane >> 4;
  const int bbase = blockIdx.x * MB;
  const int ju = wv * 16 + cn;  // this wave's output column

  // stage obs tile SoA: 320 float2 loads (R4-verified mapping)
  if (tid < OBS_T * MB) {
    const int t = tid >> 4, row = tid & 15;
    float2 v = ((const float2*)obs)[t * batch + bbase + row];
    obs_sx[t][row] = v.x;
    obs_sy[t][row] = v.y;
  }
  // stage duplicated wxb tables: 3 x 4 KB = 768 float4
  for (int i = tid; i < 768; i += 512)
    ((float4*)wxb_s)[i] = ((const float4*)wxbp)[i];
  // stage h0 tile fp32 -> bf16 LDS: 16 rows x 32 float4 = 512, one per thread
  {
    int row = tid >> 5, c4 = tid & 31;
    float4 v = ((const float4*)h0)[(bbase + row) * 32 + c4];
    bf16x4 b;
    b.x = (__bf16)v.x; b.y = (__bf16)v.y; b.z = (__bf16)v.z; b.w = (__bf16)v.w;
    *(bf16x4*)&hbuf[0][row][c4 * 4] = b;
  }

  // persistent B fragments: 1 unit-group x 4 gates x 4 ksteps = 64 regs (AGPR)
  bf16x8 Bf[4][4];  // [ks][q]
  {
    const bf16x8* wp8 = (const bf16x8*)Wp;
#pragma unroll
    for (int q = 0; q < 4; ++q)
#pragma unroll
      for (int ks = 0; ks < 4; ++ks)
        Bf[ks][q] = wp8[(wv * 16 + q * 4 + ks) * 64 + lane];
  }

  // c state as f32x2 pairs: cc2[p] = c for rows (quad*4+2p, quad*4+2p+1)
  f32x2 cc2[2];
#pragma unroll
  for (int p = 0; p < 2; ++p) {
    cc2[p].x = c0[(bbase + quad * 4 + 2 * p + 0) * HID + ju];
    cc2[p].y = c0[(bbase + quad * 4 + 2 * p + 1) * HID + ju];
  }

  __syncthreads();

  f32x4 acc[4];  // [q] — initialized for step t, carried across the barrier
  ACC_INIT(0);

  int cur = 0;
#pragma unroll 1
  for (int t = 0; t < OBS_T - 1; ++t) {
    // gates += h @ (scaled W_hh)^T : ONE A-load per ks, 16 MFMAs
#pragma unroll
    for (int ks = 0; ks < 4; ++ks) {
      bf16x8 Av = *(const bf16x8*)&hbuf[cur][cn][ks * 32 + quad * 8];
#pragma unroll
      for (int q = 0; q < 4; ++q)
        acc[q] = __builtin_amdgcn_mfma_f32_16x16x32_bf16(Av, Bf[ks][q], acc[q], 0, 0, 0);
    }

    // 4 cell updates as 2 packed pair-updates (natural .xy/.zw pairs)
    const int nxt = cur ^ 1;
    {
      f32x2 hlo = cell_update_pk(acc[0].xy, acc[1].xy, acc[2].xy, acc[3].xy, cc2[0]);
      f32x2 hhi = cell_update_pk(acc[0].zw, acc[1].zw, acc[2].zw, acc[3].zw, cc2[1]);
      hbuf[nxt][quad * 4 + 0][ju] = (__bf16)hlo.x;
      hbuf[nxt][quad * 4 + 1][ju] = (__bf16)hlo.y;
      hbuf[nxt][quad * 4 + 2][ju] = (__bf16)hhi.x;
      hbuf[nxt][quad * 4 + 3][ju] = (__bf16)hhi.y;
    }

    // next step's acc-init in the barrier shadow (h-independent work)
    ACC_INIT(t + 1);
    __syncthreads();
    cur = nxt;
  }

  // peeled final step (t=19; acc pre-initialized by the loop's last shadow
  // init): h straight to global
  {
#pragma unroll
    for (int ks = 0; ks < 4; ++ks) {
      bf16x8 Av = *(const bf16x8*)&hbuf[cur][cn][ks * 32 + quad * 8];
#pragma unroll
      for (int q = 0; q < 4; ++q)
        acc[q] = __builtin_amdgcn_mfma_f32_16x16x32_bf16(Av, Bf[ks][q], acc[q], 0, 0, 0);
    }
    {
      f32x2 hlo = cell_update_pk(acc[0].xy, acc[1].xy, acc[2].xy, acc[3].xy, cc2[0]);
      f32x2 hhi = cell_update_pk(acc[0].zw, acc[1].zw, acc[2].zw, acc[3].zw, cc2[1]);
      out[(bbase + quad * 4 + 0) * HID + ju] = hlo.x;
      out[(bbase + quad * 4 + 1) * HID + ju] = hlo.y;
      out[(bbase + quad * 4 + 2) * HID + ju] = hhi.x;
      out[(bbase + quad * 4 + 3) * HID + ju] = hhi.y;
    }
  }
}

extern "C" void kernel_launch(void* const* d_in, const int* in_sizes, int n_in,
                              void* d_out, int out_size, void* d_ws, size_t ws_size,
                              hipStream_t stream) {
  const float* obs = (const float*)d_in[0];
  const float* h0 = (const float*)d_in[1];
  const float* c0 = (const float*)d_in[2];
  const float* W_emb = (const float*)d_in[3];
  const float* b_emb = (const float*)d_in[4];
  const float* W_ih = (const float*)d_in[5];
  const float* W_hh = (const float*)d_in[6];
  const float* b_ih = (const float*)d_in[7];
  const float* b_hh = (const float*)d_in[8];
  float* out = (float*)d_out;
  const int batch = in_sizes[1] / HID;

  __bf16* Wp = (__bf16*)d_ws;                      // 65536 bf16 = 128 KB
  float2* wxb = (float2*)((char*)d_ws + 131072);   // 3 x 512 duplicated f32 pairs = 12 KB

  prep_vec<<<2, 256, 0, stream>>>(W_emb, b_emb, W_ih, b_ih, b_hh, wxb);
  prep_wp<<<256, 256, 0, stream>>>(W_hh, Wp);
  lstm_fused<<<batch / MB, 512, 0, stream>>>(obs, h0, c0, Wp, (const float*)wxb, out, batch);
}